// Round 3
// baseline (6468.288 us; speedup 1.0000x reference)
//
#include <hip/hip_runtime.h>

// ---------------------------------------------------------------------------
// LayerNorm-LSTM (2 layers) + softmax head.  B=1024 T=100 D=300 U=512 C=14
// Round 6:
//   - ws_size measured ~468.7 MiB (from fillBuffer WRITE_SIZE): hoist fits.
//   - gemm_x0: upfront x@W0 for all T (125 GF, 25600 blocks) -> z0x f16
//     [t][b][2048] at 32 MiB (+400 MiB).  Per-step prob0 = h0@U0 + f16 Cin.
//   - h01 [1024][1024] f16 (h0|h1 concat) and WU1t [2048][1024] (W1t|U1t):
//     prob1 is a SINGLE K=1024 stream, 2-deep prefetch = ~105 VGPR -> no
//     spills under launch_bounds(256,2) (round-5 dual-stream needed ~140,
//     capped at 128 -> inner-loop scratch spills = prime suspect for the
//     ~45us gemm_step).
//   - pipeline skew unchanged: iter t computes z0(t) and z1(t-1), one GEMM
//     launch + one LN launch per step.
// ---------------------------------------------------------------------------

typedef _Float16 f16;
typedef _Float16 f16x8 __attribute__((ext_vector_type(8)));
typedef float f32x4 __attribute__((ext_vector_type(4)));

// ---------------------------------------------------------------------------
// W [K,N] fp32 row-major -> Bt [N,Kp] f16 row-major at column offset k_off,
// zero-padded for k in [K, Kp-k_off).
// ---------------------------------------------------------------------------
__global__ __launch_bounds__(256) void transpose_f16(
    const float* __restrict__ W, f16* __restrict__ Bt, int K, int N, int Kp,
    int k_off) {
  __shared__ float s[32][33];
  int n0 = blockIdx.x * 32, k0 = blockIdx.y * 32;
  int tid = threadIdx.x, c = tid & 31, r8 = tid >> 5;
  for (int rr = r8; rr < 32; rr += 8) {
    int k = k0 + rr;
    s[rr][c] = (k < K) ? W[(long)k * N + (n0 + c)] : 0.0f;
  }
  __syncthreads();
  for (int rr = r8; rr < 32; rr += 8)
    Bt[(long)(n0 + rr) * Kp + k_off + (k0 + c)] = (f16)s[c][rr];
}

#define MFMAS(AF, BF)                                                                   \
  acc[0][0] = __builtin_amdgcn_mfma_f32_16x16x32_f16(AF[0], BF[0], acc[0][0], 0, 0, 0); \
  acc[0][1] = __builtin_amdgcn_mfma_f32_16x16x32_f16(AF[0], BF[1], acc[0][1], 0, 0, 0); \
  acc[1][0] = __builtin_amdgcn_mfma_f32_16x16x32_f16(AF[1], BF[0], acc[1][0], 0, 0, 0); \
  acc[1][1] = __builtin_amdgcn_mfma_f32_16x16x32_f16(AF[1], BF[1], acc[1][1], 0, 0, 0); \
  acc[2][0] = __builtin_amdgcn_mfma_f32_16x16x32_f16(AF[2], BF[0], acc[2][0], 0, 0, 0); \
  acc[2][1] = __builtin_amdgcn_mfma_f32_16x16x32_f16(AF[2], BF[1], acc[2][1], 0, 0, 0); \
  acc[3][0] = __builtin_amdgcn_mfma_f32_16x16x32_f16(AF[3], BF[0], acc[3][0], 0, 0, 0); \
  acc[3][1] = __builtin_amdgcn_mfma_f32_16x16x32_f16(AF[3], BF[1], acc[3][1], 0, 0, 0);

// A row stride fixed 1024 (h01); B row stride LDB.
#define LOADAB(AF, BF, A0, B0, LDB, K0)                    \
  AF[0] = *(const f16x8*)((A0) + (K0));                    \
  AF[1] = *(const f16x8*)((A0) + 16 * 1024 + (K0));        \
  AF[2] = *(const f16x8*)((A0) + 32 * 1024 + (K0));        \
  AF[3] = *(const f16x8*)((A0) + 48 * 1024 + (K0));        \
  BF[0] = *(const f16x8*)((B0) + (K0));                    \
  BF[1] = *(const f16x8*)((B0) + 16 * (LDB) + (K0));

// ---------------------------------------------------------------------------
// Upfront GEMM: z0x[t][b][n] = (f16) sum_k x[b,t,k] * W0[k,n]
// A = x viewed [102400][300] fp32 (row r = b*100+t), B = W0t [2048][320].
// 64x128 tile, grid (16, 1600).  Phases k0=0..256 full + guarded tail 288.
// ---------------------------------------------------------------------------
#define LOADX(AF, BF, K0)                                            \
  {                                                                  \
    _Pragma("unroll") for (int i = 0; i < 4; ++i) {                  \
      f32x4 lo = *(const f32x4*)(ax + (long)i * 4800 + (K0));        \
      f32x4 hi = *(const f32x4*)(ax + (long)i * 4800 + (K0) + 4);    \
      _Pragma("unroll") for (int e = 0; e < 4; ++e) {                \
        AF[i][e] = (f16)lo[e];                                       \
        AF[i][4 + e] = (f16)hi[e];                                   \
      }                                                              \
    }                                                                \
    BF[0] = *(const f16x8*)(bw + (K0));                              \
    BF[1] = *(const f16x8*)(bw + 16 * 320 + (K0));                   \
  }

__global__ __launch_bounds__(256) void gemm_x0(
    const float* __restrict__ x, const f16* __restrict__ W0t,
    f16* __restrict__ z0x) {
  int tid = threadIdx.x;
  int lane = tid & 63, w = tid >> 6;
  int l15 = lane & 15, quad = lane >> 4;
  long bn0 = (long)blockIdx.x * 128 + w * 32;
  long bm0 = (long)blockIdx.y * 64;
  const float* ax = x + (bm0 + l15) * 300L + quad * 8;
  const f16* bw = W0t + (bn0 + l15) * 320L + quad * 8;

  f32x4 acc[4][2] = {};
  f16x8 af0[4], bf0[2], af1[4], bf1[2];
  LOADX(af0, bf0, 0)
  for (int k0 = 0; k0 < 224; k0 += 64) {
    LOADX(af1, bf1, k0 + 32)
    MFMAS(af0, bf0)
    LOADX(af0, bf0, k0 + 64)
    MFMAS(af1, bf1)
  }
  // af0 holds phase 256.  Tail phase 288: valid k in [288,300) only.
  {
#pragma unroll
    for (int i = 0; i < 4; ++i) {
      long rb = (bm0 + l15 + i * 16) * 300L;
#pragma unroll
      for (int e = 0; e < 8; ++e) {
        int k = 288 + quad * 8 + e;
        af1[i][e] = (k < 300) ? (f16)x[rb + k] : (f16)0.f;
      }
    }
    bf1[0] = *(const f16x8*)(bw + 288);
    bf1[1] = *(const f16x8*)(bw + 16 * 320 + 288);
  }
  MFMAS(af0, bf0)  // phase 256
  MFMAS(af1, bf1)  // tail

#pragma unroll
  for (int i = 0; i < 4; ++i) {
#pragma unroll
    for (int j = 0; j < 2; ++j) {
      long col = bn0 + j * 16 + l15;
#pragma unroll
      for (int r = 0; r < 4; ++r) {
        unsigned rr = (unsigned)(bm0 + i * 16 + quad * 4 + r);
        unsigned b = rr / 100u, t = rr - b * 100u;
        z0x[(long)t * 2097152 + (long)b * 2048 + col] = (f16)acc[i][j][r];
      }
    }
  }
}

// ---------------------------------------------------------------------------
// Combined per-step GEMM (pipelined layers):
//   prob 0 (blockIdx.y < 16):  zA = [x_t@W0] + h0 @ U0     (z0 at step t)
//       hoist mode: x_t@W0 read as f16 Cin (cin0, stride 2048)
//       else:       computed in-kernel from fp32 xt (row stride 30000)
//   prob 1 (blockIdx.y >= 16): zB = h01 @ WU1t  (K=1024)   (z1 at step t-1)
// h01 [1024][1024] f16: cols [0,512)=h0, [512,1024)=h1.
// WU1t [2048][1024] f16: row n = [W1t[n] | U1t[n]].
// Block tile 64x128: 4 waves, wave tile 64x32; 2-deep register prefetch.
// ---------------------------------------------------------------------------
__global__ __launch_bounds__(256, 2) void gemm_step(
    const float* __restrict__ xt, const f16* __restrict__ h01,
    const f16* __restrict__ W0t, const f16* __restrict__ U0t,
    const f16* __restrict__ WU1t, const f16* __restrict__ cin0,
    float* __restrict__ zA, float* __restrict__ zB, int do0, int do1) {
  int prob = blockIdx.y >> 4;
  if (prob ? !do1 : !do0) return;
  int tid = threadIdx.x;
  int lane = tid & 63, w = tid >> 6;
  int l15 = lane & 15, quad = lane >> 4;
  long bn0 = (long)blockIdx.x * 128 + w * 32;
  long bm0 = (long)(blockIdx.y & 15) * 64;
  long arow = (bm0 + l15) * 1024 + quad * 8;

  f32x4 acc[4][2] = {};

  if (prob == 0) {
    if (!cin0) {
      // in-kernel x_t @ W0 (K=300: phases 0..256 + guarded tail)
      const float* ax = xt + (bm0 + l15) * 30000L + quad * 8;
      const f16* bw = W0t + (bn0 + l15) * 320L + quad * 8;
#pragma unroll
      for (int k0 = 0; k0 < 288; k0 += 32) {
        f16x8 af[4], bf[2];
#pragma unroll
        for (int i = 0; i < 4; ++i) {
          f32x4 lo = *(const f32x4*)(ax + (long)i * 480000 + k0);
          f32x4 hi = *(const f32x4*)(ax + (long)i * 480000 + k0 + 4);
#pragma unroll
          for (int e = 0; e < 4; ++e) {
            af[i][e] = (f16)lo[e];
            af[i][4 + e] = (f16)hi[e];
          }
        }
        bf[0] = *(const f16x8*)(bw + k0);
        bf[1] = *(const f16x8*)(bw + 16 * 320 + k0);
        MFMAS(af, bf)
      }
      {
        f16x8 af[4], bf[2];
#pragma unroll
        for (int i = 0; i < 4; ++i) {
          long rb = (bm0 + l15 + i * 16) * 30000L;
#pragma unroll
          for (int e = 0; e < 8; ++e) {
            int k = 288 + quad * 8 + e;
            af[i][e] = (k < 300) ? (f16)xt[rb + k] : (f16)0.f;
          }
        }
        bf[0] = *(const f16x8*)(bw + 288);
        bf[1] = *(const f16x8*)(bw + 16 * 320 + 288);
        MFMAS(af, bf)
      }
    }
    // h0 @ U0: A = h01 cols [0,512), B = U0t [2048][512], K=512
    {
      const f16* a0 = h01 + arow;
      const f16* b0 = U0t + (bn0 + l15) * 512L + quad * 8;
      f16x8 af0[4], bf0[2], af1[4], bf1[2];
      LOADAB(af0, bf0, a0, b0, 512, 0)
      for (int k0 = 0; k0 < 448; k0 += 64) {
        LOADAB(af1, bf1, a0, b0, 512, k0 + 32)
        MFMAS(af0, bf0)
        LOADAB(af0, bf0, a0, b0, 512, k0 + 64)
        MFMAS(af1, bf1)
      }
      LOADAB(af1, bf1, a0, b0, 512, 480)
      MFMAS(af0, bf0)
      MFMAS(af1, bf1)
    }
  } else {
    // z1(t-1) = h01 @ WU1t, single stream K=1024
    const f16* a0 = h01 + arow;
    const f16* b0 = WU1t + (bn0 + l15) * 1024L + quad * 8;
    f16x8 af0[4], bf0[2], af1[4], bf1[2];
    LOADAB(af0, bf0, a0, b0, 1024, 0)
    for (int k0 = 0; k0 < 960; k0 += 64) {
      LOADAB(af1, bf1, a0, b0, 1024, k0 + 32)
      MFMAS(af0, bf0)
      LOADAB(af0, bf0, a0, b0, 1024, k0 + 64)
      MFMAS(af1, bf1)
    }
    LOADAB(af1, bf1, a0, b0, 1024, 992)
    MFMAS(af0, bf0)
    MFMAS(af1, bf1)
  }

  float* Z = prob ? zB : zA;
#pragma unroll
  for (int i = 0; i < 4; ++i) {
    long row = bm0 + i * 16 + quad * 4;
#pragma unroll
    for (int j = 0; j < 2; ++j) {
      long col = bn0 + j * 16 + l15;
#pragma unroll
      for (int r = 0; r < 4; ++r) {
        float v = acc[i][j][r];
        if (prob == 0 && cin0) v += (float)cin0[(row + r) * 2048 + col];
        Z[(row + r) * 2048 + col] = v;
      }
    }
  }
}

// ---------------------------------------------------------------------------
// Combined LN + gates + state update:
//   blocks [0,1024)    : layer 0, z=zA, mask time t     (if do0)
//   blocks [1024,2048) : layer 1, z=zB, mask time t-1   (if do1)
// h stored into h01 (row stride 1024, layer offset 512*layer).
// ---------------------------------------------------------------------------
__global__ __launch_bounds__(256) void ln_gates2(
    const float* __restrict__ zA, const float* __restrict__ zB,
    const float* __restrict__ g0, const float* __restrict__ be0,
    const float* __restrict__ b0, const float* __restrict__ g1,
    const float* __restrict__ be1, const float* __restrict__ b1,
    const int* __restrict__ mask, int t,
    f16* __restrict__ h01, float* __restrict__ c0, float* __restrict__ c1,
    int do0, int do1) {
  __shared__ float act[2048];
  int layer = blockIdx.x >> 10;
  if (layer ? !do1 : !do0) return;
  int b = blockIdx.x & 1023;
  const float* z = layer ? zB : zA;
  const float* gamma = layer ? g1 : g0;
  const float* beta = layer ? be1 : be0;
  const float* bias = layer ? b1 : b0;
  f16* h = h01 + layer * 512;
  float* c = layer ? c1 : c0;
  int tm = layer ? (t - 1) : t;

  int tid = threadIdx.x;
  int w = tid >> 6, lane = tid & 63;

  const float* zb = z + (long)b * 2048 + w * 512;
  float zv[8];
  float sum = 0.0f, sq = 0.0f;
#pragma unroll
  for (int i = 0; i < 8; ++i) {
    float v = zb[lane + 64 * i];
    zv[i] = v;
    sum += v;
    sq += v * v;
  }
#pragma unroll
  for (int off = 32; off; off >>= 1) {
    sum += __shfl_xor(sum, off);
    sq += __shfl_xor(sq, off);
  }
  float mu = sum * (1.0f / 512.0f);
  float var = sq * (1.0f / 512.0f) - mu * mu;
  float is = rsqrtf(var + 1e-3f);

#pragma unroll
  for (int i = 0; i < 8; ++i) {
    int k = lane + 64 * i;
    float val = gamma[w * 512 + k] * (zv[i] - mu) * is + beta[w * 512 + k] + bias[w * 512 + k];
    float a;
    if (w == 2) {
      a = 2.0f / (1.0f + __expf(-2.0f * val)) - 1.0f;  // tanh
    } else {
      a = 1.0f / (1.0f + __expf(-val));                // sigmoid
    }
    act[w * 512 + k] = a;
  }
  __syncthreads();

  bool m = mask[(long)b * 100 + tm] > 0;
#pragma unroll
  for (int i = 0; i < 2; ++i) {
    int u = tid + 256 * i;
    float co = c[(long)b * 512 + u];
    float ho = (float)h[(long)b * 1024 + u];
    float cn = act[512 + u] * co + act[u] * act[1024 + u];
    float th = 2.0f / (1.0f + __expf(-2.0f * cn)) - 1.0f;
    float hn = act[1536 + u] * th;
    h[(long)b * 1024 + u] = (f16)(m ? hn : ho);
    c[(long)b * 512 + u] = m ? cn : co;
  }
}

// ---------------------------------------------------------------------------
// Head: out[b,:] = softmax(h1[b,:] @ Wd + bd); h1 = h01 cols [512,1024)
// ---------------------------------------------------------------------------
__global__ __launch_bounds__(64) void head_kernel(
    const f16* __restrict__ h01, const float* __restrict__ Wd,
    const float* __restrict__ bd, float* __restrict__ out) {
  __shared__ float hs[512];
  __shared__ float lg[16];
  int b = blockIdx.x, tid = threadIdx.x;
#pragma unroll
  for (int i = 0; i < 8; ++i)
    hs[tid + 64 * i] = (float)h01[(long)b * 1024 + 512 + tid + 64 * i];
  __syncthreads();
  if (tid < 14) {
    float s = bd[tid];
    for (int k = 0; k < 512; ++k) s += hs[k] * Wd[k * 14 + tid];
    lg[tid] = s;
  }
  __syncthreads();
  if (tid < 14) {
    float mx = lg[0];
#pragma unroll
    for (int i = 1; i < 14; ++i) mx = fmaxf(mx, lg[i]);
    float e = __expf(lg[tid] - mx);
    float den = 0.0f;
#pragma unroll
    for (int i = 0; i < 14; ++i) den += __expf(lg[i] - mx);
    out[(long)b * 14 + tid] = e / den;
  }
}

// ---------------------------------------------------------------------------
extern "C" void kernel_launch(void* const* d_in, const int* in_sizes, int n_in,
                              void* d_out, int out_size, void* d_ws, size_t ws_size,
                              hipStream_t stream) {
  const float* x   = (const float*)d_in[0];
  const int* mask  = (const int*)d_in[1];
  const float* W0  = (const float*)d_in[2];
  const float* U0w = (const float*)d_in[3];
  const float* b0  = (const float*)d_in[4];
  const float* g0  = (const float*)d_in[5];
  const float* be0 = (const float*)d_in[6];
  const float* W1  = (const float*)d_in[7];
  const float* U1w = (const float*)d_in[8];
  const float* b1  = (const float*)d_in[9];
  const float* g1  = (const float*)d_in[10];
  const float* be1 = (const float*)d_in[11];
  const float* Wd  = (const float*)d_in[12];
  const float* bd  = (const float*)d_in[13];
  float* out = (float*)d_out;

  char* p = (char*)d_ws;
  const size_t MB = (size_t)1 << 20;
  f16*   h01  = (f16*)(p + 0);               // 2 MiB  [1024][1024]
  float* c0   = (float*)(p + 2 * MB);        // 2 MiB
  float* c1   = (float*)(p + 4 * MB);        // 2 MiB
  float* zA   = (float*)(p + 6 * MB);        // 8 MiB
  float* zB   = (float*)(p + 14 * MB);       // 8 MiB
  f16*   W0t  = (f16*)(p + 22 * MB);         // 2048*320*2  = 1.25 MiB
  f16*   U0t  = (f16*)(p + 22 * MB + 1310720);            // 2 MiB
  f16*   WU1t = (f16*)(p + 22 * MB + 1310720 + 2097152);  // 4 MiB -> ends 29.25 MiB
  f16*   z0x  = (f16*)(p + 32 * MB);         // 100*1024*2048*2 = 400 MiB -> ends 432 MiB

  const bool hoist = ws_size >= (size_t)432 * MB;

  // zero h01, c0, c1 (ws is re-poisoned before every call)
  hipMemsetAsync(p, 0, 6 * MB, stream);

  // weight prep
  transpose_f16<<<dim3(64, 10), 256, 0, stream>>>(W0,  W0t, 300, 2048, 320, 0);
  transpose_f16<<<dim3(64, 16), 256, 0, stream>>>(U0w, U0t, 512, 2048, 512, 0);
  transpose_f16<<<dim3(64, 16), 256, 0, stream>>>(W1,  WU1t, 512, 2048, 1024, 0);
  transpose_f16<<<dim3(64, 16), 256, 0, stream>>>(U1w, WU1t, 512, 2048, 1024, 512);

  if (hoist) {
    gemm_x0<<<dim3(16, 1600), 256, 0, stream>>>(x, W0t, z0x);
  }

  // pipelined: iteration t computes z0(t) and z1(t-1) together.
  for (int t = 0; t <= 100; ++t) {
    int do0 = (t < 100) ? 1 : 0;
    int do1 = (t >= 1) ? 1 : 0;
    const f16* cin0 = hoist ? (z0x + (long)t * 2097152) : nullptr;
    gemm_step<<<dim3(16, 32), 256, 0, stream>>>(
        x + (long)t * 300, h01, W0t, U0t, WU1t, cin0, zA, zB, do0, do1);
    ln_gates2<<<2048, 256, 0, stream>>>(
        zA, zB, g0, be0, b0, g1, be1, b1, mask, t, h01, c0, c1, do0, do1);
  }

  head_kernel<<<1024, 64, 0, stream>>>(h01, Wd, bd, out);
}

// Round 4
// 5923.393 us; speedup vs baseline: 1.0920x; 1.0920x over previous
//
#include <hip/hip_runtime.h>

// ---------------------------------------------------------------------------
// LayerNorm-LSTM (2 layers) + softmax head.  B=1024 T=100 D=300 U=512 C=14
// Round 7:
//   - r6 counters: gemm_x0 983us, FETCH 497MB (x re-reads + f16-scatter
//     write-allocate RMW).  Fix: LDS-staged coalesced epilogue (64B chunks).
//   - gemm_step was ~40us vs ~5us L2-BW floor: latency-bound (2-deep
//     prefetch = 40cy slack vs ~250-600cy hit latency).  Fix: 4-deep
//     register pipeline (static names, ~143 VGPR, no spill at 2 blk/CU).
//   - ln_gates2: f32x4-vectorized loads/stores.
//   - structure unchanged: hoisted x@W0 (fits: ws ~468.7 MiB measured),
//     pipelined steps (z0(t) || z1(t-1)), 2 launches/step.
// ---------------------------------------------------------------------------

typedef _Float16 f16;
typedef _Float16 f16x8 __attribute__((ext_vector_type(8)));
typedef float f32x4 __attribute__((ext_vector_type(4)));

// ---------------------------------------------------------------------------
// W [K,N] fp32 row-major -> Bt [N,Kp] f16 row-major at column offset k_off,
// zero-padded for k in [K, Kp-k_off).
// ---------------------------------------------------------------------------
__global__ __launch_bounds__(256) void transpose_f16(
    const float* __restrict__ W, f16* __restrict__ Bt, int K, int N, int Kp,
    int k_off) {
  __shared__ float s[32][33];
  int n0 = blockIdx.x * 32, k0 = blockIdx.y * 32;
  int tid = threadIdx.x, c = tid & 31, r8 = tid >> 5;
  for (int rr = r8; rr < 32; rr += 8) {
    int k = k0 + rr;
    s[rr][c] = (k < K) ? W[(long)k * N + (n0 + c)] : 0.0f;
  }
  __syncthreads();
  for (int rr = r8; rr < 32; rr += 8)
    Bt[(long)(n0 + rr) * Kp + k_off + (k0 + c)] = (f16)s[c][rr];
}

#define MFMAS(AF, BF)                                                                   \
  acc[0][0] = __builtin_amdgcn_mfma_f32_16x16x32_f16(AF[0], BF[0], acc[0][0], 0, 0, 0); \
  acc[0][1] = __builtin_amdgcn_mfma_f32_16x16x32_f16(AF[0], BF[1], acc[0][1], 0, 0, 0); \
  acc[1][0] = __builtin_amdgcn_mfma_f32_16x16x32_f16(AF[1], BF[0], acc[1][0], 0, 0, 0); \
  acc[1][1] = __builtin_amdgcn_mfma_f32_16x16x32_f16(AF[1], BF[1], acc[1][1], 0, 0, 0); \
  acc[2][0] = __builtin_amdgcn_mfma_f32_16x16x32_f16(AF[2], BF[0], acc[2][0], 0, 0, 0); \
  acc[2][1] = __builtin_amdgcn_mfma_f32_16x16x32_f16(AF[2], BF[1], acc[2][1], 0, 0, 0); \
  acc[3][0] = __builtin_amdgcn_mfma_f32_16x16x32_f16(AF[3], BF[0], acc[3][0], 0, 0, 0); \
  acc[3][1] = __builtin_amdgcn_mfma_f32_16x16x32_f16(AF[3], BF[1], acc[3][1], 0, 0, 0);

// A row stride fixed 1024 (h01); B row stride LDB.
#define LOADAB(AF, BF, A0, B0, LDB, K0)                    \
  AF[0] = *(const f16x8*)((A0) + (K0));                    \
  AF[1] = *(const f16x8*)((A0) + 16 * 1024 + (K0));        \
  AF[2] = *(const f16x8*)((A0) + 32 * 1024 + (K0));        \
  AF[3] = *(const f16x8*)((A0) + 48 * 1024 + (K0));        \
  BF[0] = *(const f16x8*)((B0) + (K0));                    \
  BF[1] = *(const f16x8*)((B0) + 16 * (LDB) + (K0));

// 4-deep register-pipelined K-loop (KTOT multiple of 128, >= 256).
#define GEMM_PIPE4(A0, B0, LDB, KTOT)                            \
  {                                                              \
    f16x8 aA[4], bA[2], aB[4], bB[2];                            \
    f16x8 aC[4], bC[2], aD[4], bD[2];                            \
    LOADAB(aA, bA, A0, B0, LDB, 0)                               \
    LOADAB(aB, bB, A0, B0, LDB, 32)                              \
    LOADAB(aC, bC, A0, B0, LDB, 64)                              \
    LOADAB(aD, bD, A0, B0, LDB, 96)                              \
    for (int k0 = 0; k0 + 224 < (KTOT); k0 += 128) {             \
      MFMAS(aA, bA) LOADAB(aA, bA, A0, B0, LDB, k0 + 128)        \
      MFMAS(aB, bB) LOADAB(aB, bB, A0, B0, LDB, k0 + 160)        \
      MFMAS(aC, bC) LOADAB(aC, bC, A0, B0, LDB, k0 + 192)       \
      MFMAS(aD, bD) LOADAB(aD, bD, A0, B0, LDB, k0 + 224)        \
    }                                                            \
    MFMAS(aA, bA) MFMAS(aB, bB) MFMAS(aC, bC) MFMAS(aD, bD)      \
  }

// ---------------------------------------------------------------------------
// Upfront GEMM: z0x[t][b][n] = (f16) sum_k x[b,t,k] * W0[k,n]
// A = x viewed [102400][300] fp32 (row r = b*100+t), B = W0t [2048][320].
// 64x128 tile, grid (16, 1600).  LDS-staged coalesced epilogue (no RMW).
// ---------------------------------------------------------------------------
#define LOADX(AF, BF, K0)                                            \
  {                                                                  \
    _Pragma("unroll") for (int i = 0; i < 4; ++i) {                  \
      f32x4 lo = *(const f32x4*)(ax + (long)i * 4800 + (K0));        \
      f32x4 hi = *(const f32x4*)(ax + (long)i * 4800 + (K0) + 4);    \
      _Pragma("unroll") for (int e = 0; e < 4; ++e) {                \
        AF[i][e] = (f16)lo[e];                                       \
        AF[i][4 + e] = (f16)hi[e];                                   \
      }                                                              \
    }                                                                \
    BF[0] = *(const f16x8*)(bw + (K0));                              \
    BF[1] = *(const f16x8*)(bw + 16 * 320 + (K0));                   \
  }

__global__ __launch_bounds__(256) void gemm_x0(
    const float* __restrict__ x, const f16* __restrict__ W0t,
    f16* __restrict__ z0x) {
  __shared__ f16 st[64][136];  // padded: 272B row stride, 16B aligned
  int tid = threadIdx.x;
  int lane = tid & 63, w = tid >> 6;
  int l15 = lane & 15, quad = lane >> 4;
  long bn0 = (long)blockIdx.x * 128 + w * 32;
  long bm0 = (long)blockIdx.y * 64;
  const float* ax = x + (bm0 + l15) * 300L + quad * 8;
  const f16* bw = W0t + (bn0 + l15) * 320L + quad * 8;

  f32x4 acc[4][2] = {};
  f16x8 af0[4], bf0[2], af1[4], bf1[2];
  LOADX(af0, bf0, 0)
  for (int k0 = 0; k0 < 224; k0 += 64) {
    LOADX(af1, bf1, k0 + 32)
    MFMAS(af0, bf0)
    LOADX(af0, bf0, k0 + 64)
    MFMAS(af1, bf1)
  }
  // af0 holds phase 256.  Tail phase 288: valid k in [288,300) only.
  {
#pragma unroll
    for (int i = 0; i < 4; ++i) {
      long rb = (bm0 + l15 + i * 16) * 300L;
#pragma unroll
      for (int e = 0; e < 8; ++e) {
        int k = 288 + quad * 8 + e;
        af1[i][e] = (k < 300) ? (f16)x[rb + k] : (f16)0.f;
      }
    }
    bf1[0] = *(const f16x8*)(bw + 288);
    bf1[1] = *(const f16x8*)(bw + 16 * 320 + 288);
  }
  MFMAS(af0, bf0)  // phase 256
  MFMAS(af1, bf1)  // tail

  // stage to LDS (wave w owns cols [w*32, w*32+32))
#pragma unroll
  for (int i = 0; i < 4; ++i)
#pragma unroll
    for (int j = 0; j < 2; ++j)
#pragma unroll
      for (int r = 0; r < 4; ++r)
        st[i * 16 + quad * 4 + r][w * 32 + j * 16 + l15] = (f16)acc[i][j][r];
  __syncthreads();

  // coalesced write: thread tid -> row tid/4, 32 f16 (64B) at col (tid%4)*32
  {
    int r = tid >> 2, cc = (tid & 3) * 32;
    unsigned rr = (unsigned)(bm0 + r);
    unsigned b = rr / 100u, t = rr - b * 100u;
    f16* dst = z0x + (long)t * 2097152 + (long)b * 2048 + (long)blockIdx.x * 128 + cc;
    const f16x8* s8 = (const f16x8*)&st[r][cc];
    f16x8* d8 = (f16x8*)dst;
    d8[0] = s8[0]; d8[1] = s8[1]; d8[2] = s8[2]; d8[3] = s8[3];
  }
}

// ---------------------------------------------------------------------------
// Combined per-step GEMM (pipelined layers):
//   prob 0 (blockIdx.y < 16):  zA = [x_t@W0] + h0 @ U0     (z0 at step t)
//       hoist mode: x_t@W0 read as f16 Cin (cin0, stride 2048)
//       else:       computed in-kernel from fp32 xt (row stride 30000)
//   prob 1 (blockIdx.y >= 16): zB = h01 @ WU1t  (K=1024)   (z1 at step t-1)
// h01 [1024][1024] f16: cols [0,512)=h0, [512,1024)=h1.
// WU1t [2048][1024] f16: row n = [W1t[n] | U1t[n]].
// Block tile 64x128: 4 waves, wave tile 64x32; 4-deep register prefetch.
// ---------------------------------------------------------------------------
__global__ __launch_bounds__(256, 2) void gemm_step(
    const float* __restrict__ xt, const f16* __restrict__ h01,
    const f16* __restrict__ W0t, const f16* __restrict__ U0t,
    const f16* __restrict__ WU1t, const f16* __restrict__ cin0,
    float* __restrict__ zA, float* __restrict__ zB, int do0, int do1) {
  int prob = blockIdx.y >> 4;
  if (prob ? !do1 : !do0) return;
  int tid = threadIdx.x;
  int lane = tid & 63, w = tid >> 6;
  int l15 = lane & 15, quad = lane >> 4;
  long bn0 = (long)blockIdx.x * 128 + w * 32;
  long bm0 = (long)(blockIdx.y & 15) * 64;
  long arow = (bm0 + l15) * 1024 + quad * 8;

  f32x4 acc[4][2] = {};

  if (prob == 0) {
    if (!cin0) {
      // in-kernel x_t @ W0 (K=300: phases 0..256 + guarded tail)
      const float* ax = xt + (bm0 + l15) * 30000L + quad * 8;
      const f16* bw = W0t + (bn0 + l15) * 320L + quad * 8;
#pragma unroll
      for (int k0 = 0; k0 < 288; k0 += 32) {
        f16x8 af[4], bf[2];
#pragma unroll
        for (int i = 0; i < 4; ++i) {
          f32x4 lo = *(const f32x4*)(ax + (long)i * 480000 + k0);
          f32x4 hi = *(const f32x4*)(ax + (long)i * 480000 + k0 + 4);
#pragma unroll
          for (int e = 0; e < 4; ++e) {
            af[i][e] = (f16)lo[e];
            af[i][4 + e] = (f16)hi[e];
          }
        }
        bf[0] = *(const f16x8*)(bw + k0);
        bf[1] = *(const f16x8*)(bw + 16 * 320 + k0);
        MFMAS(af, bf)
      }
      {
        f16x8 af[4], bf[2];
#pragma unroll
        for (int i = 0; i < 4; ++i) {
          long rb = (bm0 + l15 + i * 16) * 30000L;
#pragma unroll
          for (int e = 0; e < 8; ++e) {
            int k = 288 + quad * 8 + e;
            af[i][e] = (k < 300) ? (f16)xt[rb + k] : (f16)0.f;
          }
        }
        bf[0] = *(const f16x8*)(bw + 288);
        bf[1] = *(const f16x8*)(bw + 16 * 320 + 288);
        MFMAS(af, bf)
      }
    }
    // h0 @ U0: A = h01 cols [0,512), B = U0t [2048][512], K=512
    {
      const f16* a0 = h01 + arow;
      const f16* b0 = U0t + (bn0 + l15) * 512L + quad * 8;
      GEMM_PIPE4(a0, b0, 512, 512)
    }
  } else {
    // z1(t-1) = h01 @ WU1t, single stream K=1024
    const f16* a0 = h01 + arow;
    const f16* b0 = WU1t + (bn0 + l15) * 1024L + quad * 8;
    GEMM_PIPE4(a0, b0, 1024, 1024)
  }

  float* Z = prob ? zB : zA;
#pragma unroll
  for (int i = 0; i < 4; ++i) {
    long row = bm0 + i * 16 + quad * 4;
#pragma unroll
    for (int j = 0; j < 2; ++j) {
      long col = bn0 + j * 16 + l15;
#pragma unroll
      for (int r = 0; r < 4; ++r) {
        float v = acc[i][j][r];
        if (prob == 0 && cin0) v += (float)cin0[(row + r) * 2048 + col];
        Z[(row + r) * 2048 + col] = v;
      }
    }
  }
}

// ---------------------------------------------------------------------------
// Combined LN + gates + state update (vectorized f32x4 loads):
//   blocks [0,1024)    : layer 0, z=zA, mask time t     (if do0)
//   blocks [1024,2048) : layer 1, z=zB, mask time t-1   (if do1)
// h stored into h01 (row stride 1024, layer offset 512*layer).
// ---------------------------------------------------------------------------
__global__ __launch_bounds__(256) void ln_gates2(
    const float* __restrict__ zA, const float* __restrict__ zB,
    const float* __restrict__ g0, const float* __restrict__ be0,
    const float* __restrict__ b0, const float* __restrict__ g1,
    const float* __restrict__ be1, const float* __restrict__ b1,
    const int* __restrict__ mask, int t,
    f16* __restrict__ h01, float* __restrict__ c0, float* __restrict__ c1,
    int do0, int do1) {
  __shared__ float act[2048];
  int layer = blockIdx.x >> 10;
  if (layer ? !do1 : !do0) return;
  int b = blockIdx.x & 1023;
  const float* z = layer ? zB : zA;
  const float* gamma = layer ? g1 : g0;
  const float* beta = layer ? be1 : be0;
  const float* bias = layer ? b1 : b0;
  f16* h = h01 + layer * 512;
  float* c = layer ? c1 : c0;
  int tm = layer ? (t - 1) : t;

  int tid = threadIdx.x;
  int w = tid >> 6, lane = tid & 63;

  const float* zb = z + (long)b * 2048 + w * 512;
  f32x4 zv[2];
  float sum = 0.0f, sq = 0.0f;
#pragma unroll
  for (int i = 0; i < 2; ++i) {
    f32x4 v = *(const f32x4*)(zb + lane * 4 + 256 * i);
    zv[i] = v;
#pragma unroll
    for (int e = 0; e < 4; ++e) {
      sum += v[e];
      sq += v[e] * v[e];
    }
  }
#pragma unroll
  for (int off = 32; off; off >>= 1) {
    sum += __shfl_xor(sum, off);
    sq += __shfl_xor(sq, off);
  }
  float mu = sum * (1.0f / 512.0f);
  float var = sq * (1.0f / 512.0f) - mu * mu;
  float is = rsqrtf(var + 1e-3f);

#pragma unroll
  for (int i = 0; i < 2; ++i) {
    int k = w * 512 + lane * 4 + 256 * i;
    f32x4 g = *(const f32x4*)(gamma + k);
    f32x4 be = *(const f32x4*)(beta + k);
    f32x4 bi = *(const f32x4*)(bias + k);
    f32x4 av;
#pragma unroll
    for (int e = 0; e < 4; ++e) {
      float val = g[e] * (zv[i][e] - mu) * is + be[e] + bi[e];
      float a;
      if (w == 2) {
        a = 2.0f / (1.0f + __expf(-2.0f * val)) - 1.0f;  // tanh
      } else {
        a = 1.0f / (1.0f + __expf(-val));                // sigmoid
      }
      av[e] = a;
    }
    *(f32x4*)(act + k) = av;
  }
  __syncthreads();

  bool m = mask[(long)b * 100 + tm] > 0;
#pragma unroll
  for (int i = 0; i < 2; ++i) {
    int u = tid + 256 * i;
    float co = c[(long)b * 512 + u];
    float ho = (float)h[(long)b * 1024 + u];
    float cn = act[512 + u] * co + act[u] * act[1024 + u];
    float th = 2.0f / (1.0f + __expf(-2.0f * cn)) - 1.0f;
    float hn = act[1536 + u] * th;
    h[(long)b * 1024 + u] = (f16)(m ? hn : ho);
    c[(long)b * 512 + u] = m ? cn : co;
  }
}

// ---------------------------------------------------------------------------
// Head: out[b,:] = softmax(h1[b,:] @ Wd + bd); h1 = h01 cols [512,1024)
// ---------------------------------------------------------------------------
__global__ __launch_bounds__(64) void head_kernel(
    const f16* __restrict__ h01, const float* __restrict__ Wd,
    const float* __restrict__ bd, float* __restrict__ out) {
  __shared__ float hs[512];
  __shared__ float lg[16];
  int b = blockIdx.x, tid = threadIdx.x;
#pragma unroll
  for (int i = 0; i < 8; ++i)
    hs[tid + 64 * i] = (float)h01[(long)b * 1024 + 512 + tid + 64 * i];
  __syncthreads();
  if (tid < 14) {
    float s = bd[tid];
    for (int k = 0; k < 512; ++k) s += hs[k] * Wd[k * 14 + tid];
    lg[tid] = s;
  }
  __syncthreads();
  if (tid < 14) {
    float mx = lg[0];
#pragma unroll
    for (int i = 1; i < 14; ++i) mx = fmaxf(mx, lg[i]);
    float e = __expf(lg[tid] - mx);
    float den = 0.0f;
#pragma unroll
    for (int i = 0; i < 14; ++i) den += __expf(lg[i] - mx);
    out[(long)b * 14 + tid] = e / den;
  }
}

// ---------------------------------------------------------------------------
extern "C" void kernel_launch(void* const* d_in, const int* in_sizes, int n_in,
                              void* d_out, int out_size, void* d_ws, size_t ws_size,
                              hipStream_t stream) {
  const float* x   = (const float*)d_in[0];
  const int* mask  = (const int*)d_in[1];
  const float* W0  = (const float*)d_in[2];
  const float* U0w = (const float*)d_in[3];
  const float* b0  = (const float*)d_in[4];
  const float* g0  = (const float*)d_in[5];
  const float* be0 = (const float*)d_in[6];
  const float* W1  = (const float*)d_in[7];
  const float* U1w = (const float*)d_in[8];
  const float* b1  = (const float*)d_in[9];
  const float* g1  = (const float*)d_in[10];
  const float* be1 = (const float*)d_in[11];
  const float* Wd  = (const float*)d_in[12];
  const float* bd  = (const float*)d_in[13];
  float* out = (float*)d_out;

  char* p = (char*)d_ws;
  const size_t MB = (size_t)1 << 20;
  f16*   h01  = (f16*)(p + 0);               // 2 MiB  [1024][1024]
  float* c0   = (float*)(p + 2 * MB);        // 2 MiB
  float* c1   = (float*)(p + 4 * MB);        // 2 MiB
  float* zA   = (float*)(p + 6 * MB);        // 8 MiB
  float* zB   = (float*)(p + 14 * MB);       // 8 MiB
  f16*   W0t  = (f16*)(p + 22 * MB);         // 2048*320*2  = 1.25 MiB
  f16*   U0t  = (f16*)(p + 22 * MB + 1310720);            // 2 MiB
  f16*   WU1t = (f16*)(p + 22 * MB + 1310720 + 2097152);  // 4 MiB -> ends 29.25 MiB
  f16*   z0x  = (f16*)(p + 32 * MB);         // 100*1024*2048*2 = 400 MiB -> ends 432 MiB

  const bool hoist = ws_size >= (size_t)432 * MB;

  // zero h01, c0, c1 (ws is re-poisoned before every call)
  hipMemsetAsync(p, 0, 6 * MB, stream);

  // weight prep
  transpose_f16<<<dim3(64, 10), 256, 0, stream>>>(W0,  W0t, 300, 2048, 320, 0);
  transpose_f16<<<dim3(64, 16), 256, 0, stream>>>(U0w, U0t, 512, 2048, 512, 0);
  transpose_f16<<<dim3(64, 16), 256, 0, stream>>>(W1,  WU1t, 512, 2048, 1024, 0);
  transpose_f16<<<dim3(64, 16), 256, 0, stream>>>(U1w, WU1t, 512, 2048, 1024, 512);

  if (hoist) {
    gemm_x0<<<dim3(16, 1600), 256, 0, stream>>>(x, W0t, z0x);
  }

  // pipelined: iteration t computes z0(t) and z1(t-1) together.
  for (int t = 0; t <= 100; ++t) {
    int do0 = (t < 100) ? 1 : 0;
    int do1 = (t >= 1) ? 1 : 0;
    const f16* cin0 = hoist ? (z0x + (long)t * 2097152) : nullptr;
    gemm_step<<<dim3(16, 32), 256, 0, stream>>>(
        x + (long)t * 300, h01, W0t, U0t, WU1t, cin0, zA, zB, do0, do1);
    ln_gates2<<<2048, 256, 0, stream>>>(
        zA, zB, g0, be0, b0, g1, be1, b1, mask, t, h01, c0, c1, do0, do1);
  }

  head_kernel<<<1024, 64, 0, stream>>>(h01, Wd, bd, out);
}